// Round 11
// baseline (120.026 us; speedup 1.0000x reference)
//
#include <hip/hip_runtime.h>
#include <hip/hip_bf16.h>
#include <hip/hip_fp8.h>
#include <stdint.h>

// Problem: N=4096 rows, D=768 dims.
//   dist[i][j] = ||A_i - P_j||;  scores = 50 - dist;  loss = mean_i(-log_softmax(scores)_ii)
// Fixed-shift softmax (scores <= 50 always): loss_i = dist_ii + log(sum_j exp(-dist_ij))
// R11: R10's fp8 pipeline (plain mfma_f32_16x16x32_fp8_fp8, BK=128, one-barrier
// dbuf) restructured to 512-thread blocks / 8 waves / wave-tile 64x32 so two
// resident blocks give 4 waves/SIMD (R10 measured 1.5 — TLP was the wall).

#define N_ROWS 4096
#define D_DIM  768
#define GRID_DIM (N_ROWS / 128)          // 32
#define NITER (D_DIM / 128)              // 6 (BK=128 fp8 bytes = 128 B rows)

typedef float f32x4 __attribute__((ext_vector_type(4)));

// ---------------- kernel 1: fp32 -> fp8 e4m3 cast + row norms + zero S -----------
__global__ __launch_bounds__(256) void cvt_norms(
        const float* __restrict__ A, const float* __restrict__ P,
        uint8_t* __restrict__ A8, uint8_t* __restrict__ P8,
        float* __restrict__ a2, float* __restrict__ p2, float* __restrict__ S) {
    const int t = threadIdx.x, lane = t & 63, wave = t >> 6;
    const int row = blockIdx.x * 4 + wave;
    const float* src = blockIdx.y ? P : A;
    uint8_t* dst = blockIdx.y ? P8 : A8;
    float* nrm = blockIdx.y ? p2 : a2;

    const float4* s4 = (const float4*)src + (size_t)row * (D_DIM / 4);
    uint32_t* d4 = (uint32_t*)dst + (size_t)row * (D_DIM / 4);
    float s = 0.0f;
#pragma unroll
    for (int c = 0; c < 3; c++) {
        float4 v = s4[c * 64 + lane];
        s += v.x * v.x + v.y * v.y + v.z * v.z + v.w * v.w;
        union { uint32_t u; uint8_t b[4]; } pk;
        pk.b[0] = __hip_fp8_e4m3(v.x).__x;
        pk.b[1] = __hip_fp8_e4m3(v.y).__x;
        pk.b[2] = __hip_fp8_e4m3(v.z).__x;
        pk.b[3] = __hip_fp8_e4m3(v.w).__x;
        d4[c * 64 + lane] = pk.u;
    }
    for (int off = 32; off; off >>= 1) s += __shfl_down(s, off);
    if (lane == 0) {
        nrm[row] = s;
        if (blockIdx.y == 0) S[row] = 0.0f;
    }
}

// ---------------- kernel 2: double-buffered fp8 MFMA GEMM + softmax epilogue -----
// 128x128 C-tile / 512-thread block; 8 waves in a 2x4 grid of 64x32 wave tiles
// (A-frags 4, B-frags 2, acc 4x2 = 32 VGPR). BK=128 fp8 = 128 B LDS rows, XOR
// chunk swizzle (write side proven conflict-free). One barrier per K-iter (R7):
// wait vmcnt(0) on tile k (issued a full iteration ago), s_barrier, stage k+1
// into the other buffer, compute k. 2 blocks/CU -> 4 waves/SIMD hides LDS/skew.
__device__ __forceinline__ void g2l16(const void* g, void* l) {
    __builtin_amdgcn_global_load_lds(
        (const __attribute__((address_space(1))) void*)g,
        (__attribute__((address_space(3))) void*)l, 16, 0, 0);
}

__global__ __launch_bounds__(512, 4) void gemm_fused(
        const uint8_t* __restrict__ A8, const uint8_t* __restrict__ P8,
        const float* __restrict__ a2, const float* __restrict__ p2,
        float* __restrict__ S, float* __restrict__ Dd) {
    __shared__ __align__(16) uint8_t As[2][128 * 128];   // 2 x 16 KB
    __shared__ __align__(16) uint8_t Bs[2][128 * 128];   // 2 x 16 KB

    const int bm = blockIdx.x, bn = blockIdx.y;
    const int t = threadIdx.x;
    const int lane = t & 63, wave = t >> 6;
    const int wm = wave >> 2, wn = wave & 3;   // wm 0..1 (64 rows), wn 0..3 (32 cols)

    f32x4 acc[4][2];
#pragma unroll
    for (int i = 0; i < 4; i++)
#pragma unroll
        for (int j = 0; j < 2; j++) acc[i][j] = (f32x4){0.f, 0.f, 0.f, 0.f};

    // staging (512 threads): 16B chunk p = c*512+t holds row r = c*64 + (t>>3),
    // swizzled global chunk sg = (t&7) ^ (r&7)  (c-invariant: c*64 % 8 == 0).
    const int rT = t >> 3;
    const int sg = (t & 7) ^ (rT & 7);
    const size_t aBase = (size_t)(bm * 128 + rT) * D_DIM + (size_t)sg * 16;
    const size_t bBase = (size_t)(bn * 128 + rT) * D_DIM + (size_t)sg * 16;

    // LDS->frag read indices (bytes). row stride 128 B; swizzle key xr = fr&7.
    const int fr = lane & 15, fq = lane >> 4;
    const int xr = fr & 7;
    const int aRow = (wm * 64 + fr) * 128;
    const int bRow = (wn * 32 + fr) * 128;
    const int qh = fq >> 1, qb = (fq & 1) * 8;   // chunk-half select within 32B

#define STAGE(K2, SEL)                                                             \
    do {                                                                           \
        const int k0_ = (K2) * 128;                                                \
        _Pragma("unroll")                                                          \
        for (int c = 0; c < 2; c++)                                                \
            g2l16(A8 + aBase + c * (64 * D_DIM) + k0_, &As[SEL][(c * 512 + t) * 16]); \
        _Pragma("unroll")                                                          \
        for (int c = 0; c < 2; c++)                                                \
            g2l16(P8 + bBase + c * (64 * D_DIM) + k0_, &Bs[SEL][(c * 512 + t) * 16]); \
    } while (0)

    STAGE(0, 0);

    for (int k = 0; k < NITER; k++) {
        const int cur = k & 1;
        // Only tile k's 4 loads outstanding, issued one full compute phase ago.
        asm volatile("s_waitcnt vmcnt(0)" ::: "memory");
        asm volatile("s_barrier" ::: "memory");
        if (k + 1 < NITER) STAGE(k + 1, cur ^ 1);   // fly during compute below

#pragma unroll
        for (int s = 0; s < 4; s++) {
            const int co = ((2 * s + qh) ^ xr) * 16 + qb;   // swizzled byte offset
            long long af[4], bfr[2];
#pragma unroll
            for (int mi = 0; mi < 4; mi++)
                af[mi] = *(const long long*)&As[cur][aRow + mi * (16 * 128) + co];
#pragma unroll
            for (int ni = 0; ni < 2; ni++)
                bfr[ni] = *(const long long*)&Bs[cur][bRow + ni * (16 * 128) + co];
#pragma unroll
            for (int mi = 0; mi < 4; mi++)
#pragma unroll
                for (int ni = 0; ni < 2; ni++)
                    acc[mi][ni] = __builtin_amdgcn_mfma_f32_16x16x32_fp8_fp8(
                        af[mi], bfr[ni], acc[mi][ni], 0, 0, 0);
        }
    }
#undef STAGE

    // ---- epilogue: dist -> exp(-dist), per-row partial sums, diagonal capture ----
    // C/D layout (16x16, shape-determined): col = lane&15, row = (lane>>4)*4 + reg
    float p2v[2];
#pragma unroll
    for (int ni = 0; ni < 2; ni++)
        p2v[ni] = p2[bn * 128 + wn * 32 + ni * 16 + fr];
    const int colBase = bn * 128 + wn * 32 + fr;

#pragma unroll
    for (int mi = 0; mi < 4; mi++) {
#pragma unroll
        for (int r = 0; r < 4; r++) {
            const int gi = bm * 128 + wm * 64 + mi * 16 + (lane >> 4) * 4 + r;
            const float a2v = a2[gi];
            float rs = 0.0f;
#pragma unroll
            for (int ni = 0; ni < 2; ni++) {
                const float cross = acc[mi][ni][r];
                const float sq = a2v + p2v[ni] - 2.0f * cross;
                const float dist = sqrtf(fmaxf(sq, 0.0f) + 1e-12f);
                const int gj = colBase + ni * 16;
                if (gi == gj) Dd[gi] = dist;
                rs += __expf(-dist);
            }
            rs += __shfl_xor(rs, 1);
            rs += __shfl_xor(rs, 2);
            rs += __shfl_xor(rs, 4);
            rs += __shfl_xor(rs, 8);
            if (fr == 0) atomicAdd(&S[gi], rs);
        }
    }
}

// ---------------- kernel 3: final reduce -> scalar -------------------------------
__global__ void finalize(const float* __restrict__ S, const float* __restrict__ Dd,
                         float* __restrict__ out) {
    const int t = threadIdx.x;
    float s = 0.0f;
    for (int i = t; i < N_ROWS; i += 256) s += Dd[i] + logf(S[i]);
    for (int off = 32; off; off >>= 1) s += __shfl_down(s, off);
    __shared__ float wsum[4];
    if ((t & 63) == 0) wsum[t >> 6] = s;
    __syncthreads();
    if (t == 0) out[0] = (wsum[0] + wsum[1] + wsum[2] + wsum[3]) * (1.0f / N_ROWS);
}

// ---------------- fallback (undersized workspace): naive fp32 --------------------
__global__ void zero_out1(float* __restrict__ out) {
    if (threadIdx.x == 0 && blockIdx.x == 0) out[0] = 0.0f;
}
__global__ void naive_row(const float* __restrict__ A, const float* __restrict__ P,
                          float* __restrict__ out) {
    __shared__ float arow[D_DIM];
    const int i = blockIdx.x, t = threadIdx.x;
    for (int c = t; c < D_DIM; c += 256) arow[c] = A[(size_t)i * D_DIM + c];
    __syncthreads();
    float sumexp = 0.0f, ddiag = 0.0f;
    for (int j = t; j < N_ROWS; j += 256) {
        const float* p = P + (size_t)j * D_DIM;
        float d2 = 0.0f;
        for (int c = 0; c < D_DIM; c++) { float df = arow[c] - p[c]; d2 += df * df; }
        float dist = sqrtf(fmaxf(d2, 0.0f) + 1e-12f);
        if (j == i) ddiag = dist;
        sumexp += __expf(-dist);
    }
    for (int off = 32; off; off >>= 1) {
        sumexp += __shfl_down(sumexp, off);
        ddiag  += __shfl_down(ddiag, off);
    }
    __shared__ float w1[4], w2[4];
    if ((t & 63) == 0) { w1[t >> 6] = sumexp; w2[t >> 6] = ddiag; }
    __syncthreads();
    if (t == 0) {
        float se = w1[0] + w1[1] + w1[2] + w1[3];
        float dd = w2[0] + w2[1] + w2[2] + w2[3];
        atomicAdd(out, (dd + logf(se)) * (1.0f / N_ROWS));
    }
}

extern "C" void kernel_launch(void* const* d_in, const int* in_sizes, int n_in,
                              void* d_out, int out_size, void* d_ws, size_t ws_size,
                              hipStream_t stream) {
    const float* A = (const float*)d_in[0];
    const float* P = (const float*)d_in[1];
    float* out = (float*)d_out;

    const size_t F8_BYTES = (size_t)N_ROWS * D_DIM;          // 3145728 per matrix
    const size_t V_BYTES  = (size_t)N_ROWS * sizeof(float);  // 16384
    const size_t NEED = 2 * F8_BYTES + 4 * V_BYTES;

    if (ws_size >= NEED) {
        char* ws = (char*)d_ws;
        uint8_t* A8 = (uint8_t*)(ws);
        uint8_t* P8 = (uint8_t*)(ws + F8_BYTES);
        float* a2 = (float*)(ws + 2 * F8_BYTES);
        float* p2 = (float*)(ws + 2 * F8_BYTES + V_BYTES);
        float* S  = (float*)(ws + 2 * F8_BYTES + 2 * V_BYTES);
        float* Dd = (float*)(ws + 2 * F8_BYTES + 3 * V_BYTES);

        hipLaunchKernelGGL(cvt_norms, dim3(N_ROWS / 4, 2), dim3(256), 0, stream,
                           A, P, A8, P8, a2, p2, S);
        hipLaunchKernelGGL(gemm_fused, dim3(GRID_DIM, GRID_DIM), dim3(512), 0, stream,
                           A8, P8, a2, p2, S, Dd);
        hipLaunchKernelGGL(finalize, dim3(1), dim3(256), 0, stream, S, Dd, out);
    } else {
        hipLaunchKernelGGL(zero_out1, dim3(1), dim3(64), 0, stream, out);
        hipLaunchKernelGGL(naive_row, dim3(N_ROWS), dim3(256), 0, stream, A, P, out);
    }
}

// Round 12
// 115.138 us; speedup vs baseline: 1.0424x; 1.0424x over previous
//
#include <hip/hip_runtime.h>
#include <hip/hip_bf16.h>
#include <hip/hip_fp8.h>
#include <stdint.h>

// Problem: N=4096 rows, D=768 dims.
//   dist[i][j] = ||A_i - P_j||;  scores = 50 - dist;  loss = mean_i(-log_softmax(scores)_ii)
// Fixed-shift softmax (scores <= 50 always): loss_i = dist_ii + log(sum_j exp(-dist_ij))
// R12: fp8 GEMM with K-PERMUTED storage. cvt_norms stores each 128B k-block with
// granule transpose (8B granule at 32s+8q -> 32q+8s, same for A and P: dot product
// invariant). Result: each lane-quad's 4 k-steps are two contiguous 16B chunks ->
// fragment loads become pure ds_read_b128 (both halves used), the exact pattern
// that measured 0 bank conflicts in R2/R5/R7. 4 MFMA per LDS read (R10: 2, R11: 1.3).

#define N_ROWS 4096
#define D_DIM  768
#define GRID_DIM (N_ROWS / 128)          // 32
#define NITER (D_DIM / 128)              // 6 (BK=128 fp8 bytes = 128 B rows)

typedef float f32x4 __attribute__((ext_vector_type(4)));
typedef int   i32x4 __attribute__((ext_vector_type(4)));

// ---------------- kernel 1: fp32 -> fp8 e4m3 cast (k-permuted) + norms + zero S --
// Word w (4B) within each 32-word (128B) block: w = 8s+2q+h  ->  w' = 8q+2s+h.
__global__ __launch_bounds__(256) void cvt_norms(
        const float* __restrict__ A, const float* __restrict__ P,
        uint8_t* __restrict__ A8, uint8_t* __restrict__ P8,
        float* __restrict__ a2, float* __restrict__ p2, float* __restrict__ S) {
    const int t = threadIdx.x, lane = t & 63, wave = t >> 6;
    const int row = blockIdx.x * 4 + wave;
    const float* src = blockIdx.y ? P : A;
    uint8_t* dst = blockIdx.y ? P8 : A8;
    float* nrm = blockIdx.y ? p2 : a2;

    const float4* s4 = (const float4*)src + (size_t)row * (D_DIM / 4);
    uint32_t* d4 = (uint32_t*)dst + (size_t)row * (D_DIM / 4);
    float s = 0.0f;
#pragma unroll
    for (int c = 0; c < 3; c++) {
        const int wf = c * 64 + lane;            // word index in row (0..191)
        float4 v = s4[wf];
        s += v.x * v.x + v.y * v.y + v.z * v.z + v.w * v.w;
        union { uint32_t u; uint8_t b[4]; } pk;
        pk.b[0] = __hip_fp8_e4m3(v.x).__x;
        pk.b[1] = __hip_fp8_e4m3(v.y).__x;
        pk.b[2] = __hip_fp8_e4m3(v.z).__x;
        pk.b[3] = __hip_fp8_e4m3(v.w).__x;
        const int w = wf & 31;                   // word within 128B block
        const int wp = (((w >> 1) & 3) << 3) | ((w >> 3) << 1) | (w & 1);  // s<->q
        d4[(wf & ~31) | wp] = pk.u;
    }
    for (int off = 32; off; off >>= 1) s += __shfl_down(s, off);
    if (lane == 0) {
        nrm[row] = s;
        if (blockIdx.y == 0) S[row] = 0.0f;
    }
}

// ---------------- kernel 2: double-buffered fp8 MFMA GEMM + softmax epilogue -----
// 128x128 C-tile / 256-thread block (2x2 waves, 64x64 each), BK=128 fp8 = 128 B
// LDS rows, XOR chunk swizzle (write side unchanged from R10). One barrier per
// K-iter (R7 schedule). Fragment reads: lane quad fq owns chunks 2fq, 2fq+1
// (k-permuted storage), each b128 = 2 k-steps, both 8B halves used.
__device__ __forceinline__ void g2l16(const void* g, void* l) {
    __builtin_amdgcn_global_load_lds(
        (const __attribute__((address_space(1))) void*)g,
        (__attribute__((address_space(3))) void*)l, 16, 0, 0);
}

__global__ __launch_bounds__(256) void gemm_fused(
        const uint8_t* __restrict__ A8, const uint8_t* __restrict__ P8,
        const float* __restrict__ a2, const float* __restrict__ p2,
        float* __restrict__ S, float* __restrict__ Dd) {
    __shared__ __align__(16) uint8_t As[2][128 * 128];   // 2 x 16 KB
    __shared__ __align__(16) uint8_t Bs[2][128 * 128];   // 2 x 16 KB

    const int bm = blockIdx.x, bn = blockIdx.y;
    const int t = threadIdx.x;
    const int lane = t & 63, wave = t >> 6;
    const int wm = wave >> 1, wn = wave & 1;

    f32x4 acc[4][4];
#pragma unroll
    for (int i = 0; i < 4; i++)
#pragma unroll
        for (int j = 0; j < 4; j++) acc[i][j] = (f32x4){0.f, 0.f, 0.f, 0.f};

    // staging: physical 16B chunk p = c*256+t holds global row r = c*32 + (t>>3),
    // swizzled global chunk sg = (t&7) ^ (r&7)  (c-invariant: c*32 % 8 == 0).
    const int rT = t >> 3;
    const int sg = (t & 7) ^ (rT & 7);
    const size_t aBase = (size_t)(bm * 128 + rT) * D_DIM + (size_t)sg * 16;
    const size_t bBase = (size_t)(bn * 128 + rT) * D_DIM + (size_t)sg * 16;

    // LDS->frag read indices (bytes). row stride 128 B; swizzle key xr = fr&7.
    const int fr = lane & 15, fq = lane >> 4;
    const int xr = fr & 7;
    const int aRow = (wm * 64 + fr) * 128;
    const int bRow = (wn * 64 + fr) * 128;
    const int cA0 = (((fq << 1) | 0) ^ xr) * 16;   // k-steps 0,1 for this quad
    const int cA1 = (((fq << 1) | 1) ^ xr) * 16;   // k-steps 2,3

#define STAGE(K2, SEL)                                                             \
    do {                                                                           \
        const int k0_ = (K2) * 128;                                                \
        _Pragma("unroll")                                                          \
        for (int c = 0; c < 4; c++)                                                \
            g2l16(A8 + aBase + c * (32 * D_DIM) + k0_, &As[SEL][(c * 256 + t) * 16]); \
        _Pragma("unroll")                                                          \
        for (int c = 0; c < 4; c++)                                                \
            g2l16(P8 + bBase + c * (32 * D_DIM) + k0_, &Bs[SEL][(c * 256 + t) * 16]); \
    } while (0)

    STAGE(0, 0);

    for (int k = 0; k < NITER; k++) {
        const int cur = k & 1;
        // Only tile k's 8 loads outstanding, issued one full compute phase ago.
        asm volatile("s_waitcnt vmcnt(0)" ::: "memory");
        asm volatile("s_barrier" ::: "memory");
        if (k + 1 < NITER) STAGE(k + 1, cur ^ 1);   // fly during compute below

#pragma unroll
        for (int h = 0; h < 2; h++) {               // h=0: k-steps 0,1; h=1: 2,3
            const int co = h ? cA1 : cA0;
            i32x4 av[4], bv[4];
#pragma unroll
            for (int mi = 0; mi < 4; mi++)
                av[mi] = *(const i32x4*)&As[cur][aRow + mi * (16 * 128) + co];
#pragma unroll
            for (int ni = 0; ni < 4; ni++)
                bv[ni] = *(const i32x4*)&Bs[cur][bRow + ni * (16 * 128) + co];
            // low 8B = first k-step, high 8B = second (granule transpose layout)
#pragma unroll
            for (int half = 0; half < 2; half++) {
#pragma unroll
                for (int mi = 0; mi < 4; mi++) {
                    const long long afh = ((const long long*)&av[mi])[half];
#pragma unroll
                    for (int ni = 0; ni < 4; ni++) {
                        const long long bfh = ((const long long*)&bv[ni])[half];
                        acc[mi][ni] = __builtin_amdgcn_mfma_f32_16x16x32_fp8_fp8(
                            afh, bfh, acc[mi][ni], 0, 0, 0);
                    }
                }
            }
        }
    }
#undef STAGE

    // ---- epilogue: dist -> exp(-dist), per-row partial sums, diagonal capture ----
    // C/D layout (16x16, shape-determined): col = lane&15, row = (lane>>4)*4 + reg
    float p2v[4];
#pragma unroll
    for (int ni = 0; ni < 4; ni++)
        p2v[ni] = p2[bn * 128 + wn * 64 + ni * 16 + fr];
    const int colBase = bn * 128 + wn * 64 + fr;

#pragma unroll
    for (int mi = 0; mi < 4; mi++) {
#pragma unroll
        for (int r = 0; r < 4; r++) {
            const int gi = bm * 128 + wm * 64 + mi * 16 + fq * 4 + r;
            const float a2v = a2[gi];
            float rs = 0.0f;
#pragma unroll
            for (int ni = 0; ni < 4; ni++) {
                const float cross = acc[mi][ni][r];
                const float sq = a2v + p2v[ni] - 2.0f * cross;
                const float dist = sqrtf(fmaxf(sq, 0.0f) + 1e-12f);
                const int gj = colBase + ni * 16;
                if (gi == gj) Dd[gi] = dist;
                rs += __expf(-dist);
            }
            rs += __shfl_xor(rs, 1);
            rs += __shfl_xor(rs, 2);
            rs += __shfl_xor(rs, 4);
            rs += __shfl_xor(rs, 8);
            if (fr == 0) atomicAdd(&S[gi], rs);
        }
    }
}

// ---------------- kernel 3: final reduce -> scalar -------------------------------
__global__ void finalize(const float* __restrict__ S, const float* __restrict__ Dd,
                         float* __restrict__ out) {
    const int t = threadIdx.x;
    float s = 0.0f;
    for (int i = t; i < N_ROWS; i += 256) s += Dd[i] + logf(S[i]);
    for (int off = 32; off; off >>= 1) s += __shfl_down(s, off);
    __shared__ float wsum[4];
    if ((t & 63) == 0) wsum[t >> 6] = s;
    __syncthreads();
    if (t == 0) out[0] = (wsum[0] + wsum[1] + wsum[2] + wsum[3]) * (1.0f / N_ROWS);
}

// ---------------- fallback (undersized workspace): naive fp32 --------------------
__global__ void zero_out1(float* __restrict__ out) {
    if (threadIdx.x == 0 && blockIdx.x == 0) out[0] = 0.0f;
}
__global__ void naive_row(const float* __restrict__ A, const float* __restrict__ P,
                          float* __restrict__ out) {
    __shared__ float arow[D_DIM];
    const int i = blockIdx.x, t = threadIdx.x;
    for (int c = t; c < D_DIM; c += 256) arow[c] = A[(size_t)i * D_DIM + c];
    __syncthreads();
    float sumexp = 0.0f, ddiag = 0.0f;
    for (int j = t; j < N_ROWS; j += 256) {
        const float* p = P + (size_t)j * D_DIM;
        float d2 = 0.0f;
        for (int c = 0; c < D_DIM; c++) { float df = arow[c] - p[c]; d2 += df * df; }
        float dist = sqrtf(fmaxf(d2, 0.0f) + 1e-12f);
        if (j == i) ddiag = dist;
        sumexp += __expf(-dist);
    }
    for (int off = 32; off; off >>= 1) {
        sumexp += __shfl_down(sumexp, off);
        ddiag  += __shfl_down(ddiag, off);
    }
    __shared__ float w1[4], w2[4];
    if ((t & 63) == 0) { w1[t >> 6] = sumexp; w2[t >> 6] = ddiag; }
    __syncthreads();
    if (t == 0) {
        float se = w1[0] + w1[1] + w1[2] + w1[3];
        float dd = w2[0] + w2[1] + w2[2] + w2[3];
        atomicAdd(out, (dd + logf(se)) * (1.0f / N_ROWS));
    }
}

extern "C" void kernel_launch(void* const* d_in, const int* in_sizes, int n_in,
                              void* d_out, int out_size, void* d_ws, size_t ws_size,
                              hipStream_t stream) {
    const float* A = (const float*)d_in[0];
    const float* P = (const float*)d_in[1];
    float* out = (float*)d_out;

    const size_t F8_BYTES = (size_t)N_ROWS * D_DIM;          // 3145728 per matrix
    const size_t V_BYTES  = (size_t)N_ROWS * sizeof(float);  // 16384
    const size_t NEED = 2 * F8_BYTES + 4 * V_BYTES;

    if (ws_size >= NEED) {
        char* ws = (char*)d_ws;
        uint8_t* A8 = (uint8_t*)(ws);
        uint8_t* P8 = (uint8_t*)(ws + F8_BYTES);
        float* a2 = (float*)(ws + 2 * F8_BYTES);
        float* p2 = (float*)(ws + 2 * F8_BYTES + V_BYTES);
        float* S  = (float*)(ws + 2 * F8_BYTES + 2 * V_BYTES);
        float* Dd = (float*)(ws + 2 * F8_BYTES + 3 * V_BYTES);

        hipLaunchKernelGGL(cvt_norms, dim3(N_ROWS / 4, 2), dim3(256), 0, stream,
                           A, P, A8, P8, a2, p2, S);
        hipLaunchKernelGGL(gemm_fused, dim3(GRID_DIM, GRID_DIM), dim3(256), 0, stream,
                           A8, P8, a2, p2, S, Dd);
        hipLaunchKernelGGL(finalize, dim3(1), dim3(256), 0, stream, S, Dd, out);
    } else {
        hipLaunchKernelGGL(zero_out1, dim3(1), dim3(64), 0, stream, out);
        hipLaunchKernelGGL(naive_row, dim3(N_ROWS), dim3(256), 0, stream, A, P, out);
    }
}